// Round 7
// baseline (368.127 us; speedup 1.0000x reference)
//
#include <hip/hip_runtime.h>

typedef _Float16 f16;
typedef _Float16 f16x8 __attribute__((ext_vector_type(8)));
typedef float f32x4 __attribute__((ext_vector_type(4)));

static constexpr size_t PART_STRIDE = (size_t)8192 * 256;

// ---------------- workspace layout (bytes) ----------------
static constexpr size_t OFF_W2   = 0;                                   // 516 steps * 8192 f16
static constexpr size_t SZ_W2    = (size_t)516 * 8192 * 2;
static constexpr size_t OFF_W3   = OFF_W2 + SZ_W2;                      // 520 steps * 8192 f16
static constexpr size_t SZ_W3    = (size_t)520 * 8192 * 2;
static constexpr size_t OFF_OT1  = OFF_W3 + SZ_W3;                      // 8192*128 f16 (row-major)
static constexpr size_t OFF_XF2  = OFF_OT1 + (size_t)8192 * 128 * 2;    // 8192*128 f16 (row-major)
static constexpr size_t OFF_C2   = OFF_XF2 + (size_t)8192 * 128 * 2;    // 256 f32
static constexpr size_t OFF_C3   = OFF_C2 + 1024;                       // 256 f32
static constexpr size_t OFF_ACC  = OFF_C3 + 1024;                       // 8192 f32
static constexpr size_t OFF_PART = OFF_ACC + 32768;                     // 4*8192*256 f32

// ---------------- weight pre-swizzle into fragment-linear f16 ----------------
// K enumeration (jw outer, i inner) so GEMM A-slices stay in registers:
//   step s, lane l, elem e: kl = (l>>4)*8+e
//   L2: s<4  -> row = 1 + s*32 + kl            (linear: ot1 cols)
//       else u=s-4:  row = 129 + (u&127)*128 + (u>>7)*32 + kl
//   L3: s<8  -> row = 1 + s*32 + kl            (linear: [ot1|xf2] cols)
//       else u=s-8:  row = 257 + (u&127)*128 + (u>>7)*32 + kl
// Wswz[((s*16 + nt)*64 + l)*8 + e] = Weff[row][n = nt*16 + (l&15)]
// element strides: step = 8192 f16, 16-col group nt = 512 f16.
template<int LAYER>
__global__ __launch_bounds__(256)
void prep_w(const float* __restrict__ Wf, const float* __restrict__ Wg,
            f16* __restrict__ Wswz)
{
    const int t = blockIdx.x * 256 + threadIdx.x;
    const int s = t >> 10, rem = t & 1023;
    const int nt = rem >> 6, l = rem & 63;
    const int n = nt * 16 + (l & 15);
    const int klb = (l >> 4) * 8;
    f16x8 o;
#pragma unroll
    for (int e = 0; e < 8; ++e) {
        const int kl = klb + e;
        int row;
        if (LAYER == 2) {
            if (s < 4) row = 1 + s * 32 + kl;
            else { const int u = s - 4; row = 129 + (u & 127) * 128 + (u >> 7) * 32 + kl; }
        } else {
            if (s < 8) row = 1 + s * 32 + kl;
            else { const int u = s - 8; row = 257 + (u & 127) * 128 + (u >> 7) * 32 + kl; }
        }
        const float v = (n < 128) ? Wf[(size_t)row * 128 + n]
                                  : Wg[(size_t)row * 128 + (n - 128)];
        o[e] = (f16)v;
    }
    *(f16x8*)(Wswz + (size_t)t * 8) = o;
}

// ---------------- bias-row constants: c[n] = b[n] + bias0 * W[0,n] ----------------
__global__ __launch_bounds__(256)
void prep_small(const float* __restrict__ bias0,
                const float* __restrict__ Wf2, const float* __restrict__ bf2,
                const float* __restrict__ Wg2, const float* __restrict__ bg2,
                const float* __restrict__ Wf3, const float* __restrict__ bf3,
                const float* __restrict__ Wg3, const float* __restrict__ bg3,
                float* __restrict__ c2, float* __restrict__ c3)
{
    const int n = threadIdx.x;
    const float b0 = bias0[0];
    if (n < 128) { c2[n] = bf2[n] + b0 * Wf2[n]; c3[n] = bf3[n] + b0 * Wf3[n]; }
    else { const int m = n - 128; c2[n] = bg2[m] + b0 * Wg2[m]; c3[n] = bg3[m] + b0 * Wg3[m]; }
}

// ---------------- layer 1: ot1/og1 + their final-dot contribution ----------------
__global__ __launch_bounds__(256)
void layer1_poly(const float* __restrict__ x, const float* __restrict__ bias0,
                 const float* __restrict__ Wf1, const float* __restrict__ bf1,
                 const float* __restrict__ Wg1, const float* __restrict__ bg1,
                 const float* __restrict__ Wfc, const float* __restrict__ bfc,
                 f16* __restrict__ ot1f16, float* __restrict__ outacc)
{
    const int half = threadIdx.x >> 7;   // 2 rows per block
    const int n = threadIdx.x & 127;
    const int r = blockIdx.x * 2 + half;
    const float b0 = bias0[0];
    float sf = b0 * Wf1[n] + bf1[n];
    float sg = b0 * Wg1[n] + bg1[n];
    const float* xr = x + (size_t)r * 64;
#pragma unroll 8
    for (int k = 0; k < 64; ++k) {
        const float xv = xr[k];
        sf = fmaf(xv, Wf1[(k + 1) * 128 + n], sf);
        sg = fmaf(xv, Wg1[(k + 1) * 128 + n], sg);
    }
    ot1f16[(size_t)r * 128 + n] = (f16)sf;     // row-major
    float p = sf * Wfc[1 + n] + sg * Wfc[385 + n];
#pragma unroll
    for (int off = 32; off; off >>= 1) p += __shfl_down(p, off);
    __shared__ float wp[4];
    if ((threadIdx.x & 63) == 0) wp[threadIdx.x >> 6] = p;
    __syncthreads();
    if ((threadIdx.x & 127) == 0)
        outacc[r] = bfc[0] + b0 * Wfc[0] + wp[half * 2] + wp[half * 2 + 1];
}

// ---------------- main GEMM v3: barrier-free, B direct global->VGPR ----------------
// Block: 256M x 32N, 4 waves (2M x 2N), wave tile 128M x 16N (mi=8, ni=1).
// Grid: 32 rb x 4 sp x 8 nb = 1024 blocks -> 4 blocks/CU, 16 waves/CU.
// No LDS, no __syncthreads: B frags are fragment-linear in global (coalesced
// 16B/lane), prefetched 2 steps ahead in rotating registers bA/bB/bC.

#define OBODY(O1CUR, O1NXT, I8)                                                     \
{                                                                                   \
    _Pragma("unroll")                                                               \
    for (int e = 0; e < 8; ++e) {                                                   \
        const int cc = (I8) * 8 + e;                                                \
        f16x8 bC = {};                                                              \
        if (cc + 2 < 128)                                                           \
            bC = *(const f16x8*)(wB + (size_t)(out_base + cc + 2) * 8192);          \
        if (e == 0) {                                                               \
            _Pragma("unroll")                                                       \
            for (int mi = 0; mi < 8; ++mi)                                          \
                O1NXT[mi] = *(const f16x8*)(ot1_row + mi * 2048 + ((I8) + 1) * 8);  \
        }                                                                           \
        _Pragma("unroll")                                                           \
        for (int mi = 0; mi < 8; ++mi) {                                            \
            const f16x8 a = featreg[mi] * O1CUR[mi][e];                             \
            acc[mi] = __builtin_amdgcn_mfma_f32_16x16x32_f16(a, bA, acc[mi], 0, 0, 0);\
        }                                                                           \
        bA = bB; bB = bC;                                                           \
    }                                                                               \
}

template<int LAYER>
__global__ __launch_bounds__(256, 4)
void gemm_poly(const f16* __restrict__ Wswz, const f16* featg,
               const f16* ot1g, float* __restrict__ partials)
{
    constexpr int NLIN = (LAYER == 2) ? 4 : 8;   // global linear k-steps
    constexpr int CLIN = (LAYER == 2) ? 1 : 2;   // linear steps per split

    const int bid = blockIdx.x;
    const int rb = bid >> 5;                 // 0..31
    const int sp = (bid >> 3) & 3;           // k-split / j-window
    const int nb = bid & 7;                  // 32-col N group (nb==XCD under bid%8)
    const int r0 = rb * 256;
    const int tid = threadIdx.x;
    const int wid = tid >> 6, lane = tid & 63;
    const int wr = wid >> 1, wc = wid & 1;   // 2M x 2N wave grid
    const int lhi = lane >> 4, llo = lane & 15;

    // per-lane B pointer: cols nt = nb*2 + wc, element (nt*64+lane)*8
    const f16* wB = Wswz + nb * 1024 + wc * 512 + lane * 8;
    const f16* ot1_row  = ot1g  + (size_t)(r0 + wr * 128 + llo) * 128;  // + mi*2048
    const f16* feat_row = featg + (size_t)(r0 + wr * 128 + llo) * 128;

    f32x4 acc[8] = {};
    const int out_base = NLIN + sp * 128;

    // prologue: register-resident A slices + first o1 block (all independent loads)
    f16x8 featreg[8], o1A[8], o1B[8];
#pragma unroll
    for (int mi = 0; mi < 8; ++mi) {
        featreg[mi] = *(const f16x8*)(feat_row + mi * 2048 + sp * 32 + lhi * 8);
        o1A[mi]     = *(const f16x8*)(ot1_row + mi * 2048);
    }
    // outer-region B prefetch issues early, overlaps linear region
    f16x8 bA = *(const f16x8*)(wB + (size_t)(out_base + 0) * 8192);
    f16x8 bB = *(const f16x8*)(wB + (size_t)(out_base + 1) * 8192);

    // ---- linear steps ----
#pragma unroll
    for (int c = 0; c < CLIN; ++c) {
        const int s = CLIN * sp + c;
        const f16x8 b = *(const f16x8*)(wB + (size_t)s * 8192);
        const int col = s * 32 + lhi * 8;
#pragma unroll
        for (int mi = 0; mi < 8; ++mi) {
            f16x8 a;
            if (LAYER == 2) a = *(const f16x8*)(ot1_row + mi * 2048 + col);
            else a = (col < 128) ? *(const f16x8*)(ot1_row + mi * 2048 + col)
                                 : *(const f16x8*)(feat_row + mi * 2048 + (col - 128));
            acc[mi] = __builtin_amdgcn_mfma_f32_16x16x32_f16(a, b, acc[mi], 0, 0, 0);
        }
    }

    // ---- outer-product region: 128 steps (j-window = sp fixed, i inner) ----
    for (int i8 = 0; i8 < 16; i8 += 2) {
        OBODY(o1A, o1B, i8);
        OBODY(o1B, o1A, i8 + 1);
    }

    // ---- epilogue: partial C (f32) ----
    float* pout = partials + (size_t)sp * PART_STRIDE
                + (size_t)(r0 + wr * 128) * 256 + nb * 32 + wc * 16 + llo;
#pragma unroll
    for (int mi = 0; mi < 8; ++mi)
#pragma unroll
        for (int q = 0; q < 4; ++q)
            pout[(size_t)(mi * 16 + lhi * 4 + q) * 256] = acc[mi][q];
}

#undef OBODY

// ---------------- K-split reduction + bias const + final-dot contribution ----------------
template<int LAYER>
__global__ __launch_bounds__(256)
void reduce_poly(const float* __restrict__ partials, const float* __restrict__ cvec,
                 const float* __restrict__ Wfc, f16* __restrict__ xf_out,
                 float* __restrict__ outacc, float* __restrict__ outp)
{
    const int r = blockIdx.x;
    const int n = threadIdx.x;
    const size_t idx = (size_t)r * 256 + n;
    float v = partials[idx] + partials[idx + PART_STRIDE]
            + partials[idx + 2 * PART_STRIDE] + partials[idx + 3 * PART_STRIDE];
    v += cvec[n];
    if (LAYER == 2 && n < 128)
        xf_out[(size_t)r * 128 + n] = (f16)v;       // row-major
    const int wseg = (LAYER == 2) ? (n < 128 ? 129 + n : 513 + (n - 128))
                                  : (n < 128 ? 257 + n : 641 + (n - 128));
    float p = v * Wfc[wseg];
#pragma unroll
    for (int off = 32; off; off >>= 1) p += __shfl_down(p, off);
    __shared__ float wp[4];
    if ((threadIdx.x & 63) == 0) wp[threadIdx.x >> 6] = p;
    __syncthreads();
    if (threadIdx.x == 0) {
        const float tot = wp[0] + wp[1] + wp[2] + wp[3];
        if (LAYER == 2) outacc[r] += tot;
        else            outp[r] = outacc[r] + tot;
    }
}

// ---------------- host launcher ----------------
extern "C" void kernel_launch(void* const* d_in, const int* in_sizes, int n_in,
                              void* d_out, int out_size, void* d_ws, size_t ws_size,
                              hipStream_t stream)
{
    (void)in_sizes; (void)n_in; (void)out_size; (void)ws_size;
    const float* x     = (const float*)d_in[0];
    const float* bias0 = (const float*)d_in[1];
    const float* Wf1   = (const float*)d_in[2];
    const float* bf1   = (const float*)d_in[3];
    const float* Wg1   = (const float*)d_in[4];
    const float* bg1   = (const float*)d_in[5];
    const float* Wf2   = (const float*)d_in[6];
    const float* bf2   = (const float*)d_in[7];
    const float* Wg2   = (const float*)d_in[8];
    const float* bg2   = (const float*)d_in[9];
    const float* Wf3   = (const float*)d_in[10];
    const float* bf3   = (const float*)d_in[11];
    const float* Wg3   = (const float*)d_in[12];
    const float* bg3   = (const float*)d_in[13];
    const float* Wfc   = (const float*)d_in[14];
    const float* bfc   = (const float*)d_in[15];
    float* out = (float*)d_out;

    char* ws = (char*)d_ws;
    f16*   W2s    = (f16*)(ws + OFF_W2);
    f16*   W3s    = (f16*)(ws + OFF_W3);
    f16*   ot1f16 = (f16*)(ws + OFF_OT1);
    f16*   xf2f16 = (f16*)(ws + OFF_XF2);
    float* c2     = (float*)(ws + OFF_C2);
    float* c3     = (float*)(ws + OFF_C3);
    float* outacc = (float*)(ws + OFF_ACC);
    float* parts  = (float*)(ws + OFF_PART);

    prep_w<2><<<2064, 256, 0, stream>>>(Wf2, Wg2, W2s);   // 516*1024/256
    prep_w<3><<<2080, 256, 0, stream>>>(Wf3, Wg3, W3s);   // 520*1024/256
    prep_small<<<1, 256, 0, stream>>>(bias0, Wf2, bf2, Wg2, bg2, Wf3, bf3, Wg3, bg3, c2, c3);
    layer1_poly<<<4096, 256, 0, stream>>>(x, bias0, Wf1, bf1, Wg1, bg1, Wfc, bfc, ot1f16, outacc);
    gemm_poly<2><<<1024, 256, 0, stream>>>(W2s, ot1f16, ot1f16, parts);
    reduce_poly<2><<<8192, 256, 0, stream>>>(parts, c2, Wfc, xf2f16, outacc, out);
    gemm_poly<3><<<1024, 256, 0, stream>>>(W3s, xf2f16, ot1f16, parts);
    reduce_poly<3><<<8192, 256, 0, stream>>>(parts, c3, Wfc, nullptr, outacc, out);
}

// Round 8
// 295.869 us; speedup vs baseline: 1.2442x; 1.2442x over previous
//
#include <hip/hip_runtime.h>

typedef _Float16 f16;
typedef _Float16 f16x8 __attribute__((ext_vector_type(8)));
typedef float f32x4 __attribute__((ext_vector_type(4)));

static constexpr size_t PART_STRIDE = (size_t)8192 * 256;

// ---------------- workspace layout (bytes) ----------------
static constexpr size_t OFF_W2   = 0;                                   // 516 steps * 8192 f16
static constexpr size_t SZ_W2    = (size_t)516 * 8192 * 2;
static constexpr size_t OFF_W3   = OFF_W2 + SZ_W2;                      // 520 steps * 8192 f16
static constexpr size_t SZ_W3    = (size_t)520 * 8192 * 2;
static constexpr size_t OFF_OT1  = OFF_W3 + SZ_W3;                      // 8192*128 f16 (row-major)
static constexpr size_t OFF_XF2  = OFF_OT1 + (size_t)8192 * 128 * 2;    // 8192*128 f16 (row-major)
static constexpr size_t OFF_C2   = OFF_XF2 + (size_t)8192 * 128 * 2;    // 256 f32
static constexpr size_t OFF_C3   = OFF_C2 + 1024;                       // 256 f32
static constexpr size_t OFF_ACC  = OFF_C3 + 1024;                       // 8192 f32
static constexpr size_t OFF_PART = OFF_ACC + 32768;                     // 4*8192*256 f32

// ---------------- fused prep: W2/W3 swizzle + bias consts + layer 1 ----------------
// K enumeration (jw outer, i inner); step s, lane l, elem e: kl=(l>>4)*8+e
//   L2: s<4  -> row = 1+s*32+kl ; else u=s-4: row = 129+(u&127)*128+(u>>7)*32+kl
//   L3: s<8  -> row = 1+s*32+kl ; else u=s-8: row = 257+(u&127)*128+(u>>7)*32+kl
// Wswz[((s*16+nt)*64+l)*8+e] = Weff[row][n=nt*16+(l&15)]; step stride 8192 f16.
template<int LAYER>
__device__ __forceinline__
void prep_w_body(int t, const float* __restrict__ Wf, const float* __restrict__ Wg,
                 f16* __restrict__ Wswz)
{
    const int s = t >> 10, rem = t & 1023;
    const int nt = rem >> 6, l = rem & 63;
    const int n = nt * 16 + (l & 15);
    const int klb = (l >> 4) * 8;
    f16x8 o;
#pragma unroll
    for (int e = 0; e < 8; ++e) {
        const int kl = klb + e;
        int row;
        if (LAYER == 2) {
            if (s < 4) row = 1 + s * 32 + kl;
            else { const int u = s - 4; row = 129 + (u & 127) * 128 + (u >> 7) * 32 + kl; }
        } else {
            if (s < 8) row = 1 + s * 32 + kl;
            else { const int u = s - 8; row = 257 + (u & 127) * 128 + (u >> 7) * 32 + kl; }
        }
        const float v = (n < 128) ? Wf[(size_t)row * 128 + n]
                                  : Wg[(size_t)row * 128 + (n - 128)];
        o[e] = (f16)v;
    }
    *(f16x8*)(Wswz + (size_t)t * 8) = o;
}

__global__ __launch_bounds__(256)
void prep_fused(const float* __restrict__ x, const float* __restrict__ bias0,
                const float* __restrict__ Wf1, const float* __restrict__ bf1,
                const float* __restrict__ Wg1, const float* __restrict__ bg1,
                const float* __restrict__ Wf2, const float* __restrict__ bf2,
                const float* __restrict__ Wg2, const float* __restrict__ bg2,
                const float* __restrict__ Wf3, const float* __restrict__ bf3,
                const float* __restrict__ Wg3, const float* __restrict__ bg3,
                const float* __restrict__ Wfc, const float* __restrict__ bfc,
                f16* __restrict__ W2s, f16* __restrict__ W3s,
                float* __restrict__ c2, float* __restrict__ c3,
                f16* __restrict__ ot1f16, float* __restrict__ outacc)
{
    const int bid = blockIdx.x;
    __shared__ float wp[4];
    if (bid < 2064) {
        prep_w_body<2>(bid * 256 + threadIdx.x, Wf2, Wg2, W2s);
    } else if (bid < 4144) {
        prep_w_body<3>((bid - 2064) * 256 + threadIdx.x, Wf3, Wg3, W3s);
    } else if (bid == 4144) {
        const int n = threadIdx.x;
        const float b0 = bias0[0];
        if (n < 128) { c2[n] = bf2[n] + b0 * Wf2[n]; c3[n] = bf3[n] + b0 * Wf3[n]; }
        else { const int m = n - 128; c2[n] = bg2[m] + b0 * Wg2[m]; c3[n] = bg3[m] + b0 * Wg3[m]; }
    } else {
        const int half = threadIdx.x >> 7;   // 2 rows per block
        const int n = threadIdx.x & 127;
        const int r = (bid - 4145) * 2 + half;
        const float b0 = bias0[0];
        float sf = b0 * Wf1[n] + bf1[n];
        float sg = b0 * Wg1[n] + bg1[n];
        const float* xr = x + (size_t)r * 64;
#pragma unroll 8
        for (int k = 0; k < 64; ++k) {
            const float xv = xr[k];
            sf = fmaf(xv, Wf1[(k + 1) * 128 + n], sf);
            sg = fmaf(xv, Wg1[(k + 1) * 128 + n], sg);
        }
        ot1f16[(size_t)r * 128 + n] = (f16)sf;     // row-major
        float p = sf * Wfc[1 + n] + sg * Wfc[385 + n];
#pragma unroll
        for (int off = 32; off; off >>= 1) p += __shfl_down(p, off);
        if ((threadIdx.x & 63) == 0) wp[threadIdx.x >> 6] = p;
        __syncthreads();
        if ((threadIdx.x & 127) == 0)
            outacc[r] = bfc[0] + b0 * Wfc[0] + wp[half * 2] + wp[half * 2 + 1];
    }
}

// ---------------- main GEMM v4: LDS ring + counted vmcnt (T3/T4) ----------------
// Block 256M x 64N, 4 waves (2M x 2N), wave tile 128M x 32N (mi=8, ni=2).
// Grid 32 rb x 4 sp x 4 nb = 512 -> 2 blocks/CU.
// 3-slot LDS ring, stage distance 2, raw s_barrier + exact counted vmcnt
// (never 0 in the main loop); dummy tail stages keep the count uniform.

#define STAGE(S_W, BUF) do {                                                        \
    const f16* _src = wsrc0 + (size_t)(S_W) * 8192;                                 \
    __builtin_amdgcn_global_load_lds(                                               \
        (const __attribute__((address_space(1))) unsigned int*)_src,                \
        (__attribute__((address_space(3))) unsigned int*)&wring[BUF][tid * 8],      \
        16, 0, 0);                                                                  \
} while (0)

#define WAITVX(N) asm volatile("s_waitcnt vmcnt(" #N ") lgkmcnt(0)" ::: "memory")
#define WAITV(N) WAITVX(N)

// One ring step. WN: exact vmcnt (literal). LN: load next o1 block at E==0.
#define RSTEP(O1CUR, O1NXT, I8, E, WN, LN)                                          \
{                                                                                   \
    const int s_ = (I8) * 8 + (E);                                                  \
    WAITV(WN);                                                                      \
    __builtin_amdgcn_s_barrier();                                                   \
    __builtin_amdgcn_sched_barrier(0);                                              \
    {                                                                               \
        const int sn_ = (s_ + 2 < 128) ? s_ + 2 : 127;   /* dummy at tail */        \
        STAGE(out_base + sn_, (s_ + 2) % 3);                                        \
    }                                                                               \
    if ((LN) && (E) == 0) {                                                         \
        _Pragma("unroll")                                                           \
        for (int mi = 0; mi < 8; ++mi)                                              \
            O1NXT[mi] = *(const f16x8*)(ot1_row + mi * 2048 + ((I8) + 1) * 8);      \
    }                                                                               \
    const f16* wb_ = &wring[s_ % 3][0];                                             \
    const f16x8 b0_ = *(const f16x8*)(wb_ + (wc * 128 + lane) * 8);                 \
    const f16x8 b1_ = *(const f16x8*)(wb_ + (wc * 128 + 64 + lane) * 8);            \
    _Pragma("unroll")                                                               \
    for (int mi = 0; mi < 8; ++mi) {                                                \
        const f16x8 a_ = featreg[mi] * O1CUR[mi][E];                                \
        acc[mi][0] = __builtin_amdgcn_mfma_f32_16x16x32_f16(a_, b0_, acc[mi][0], 0, 0, 0); \
        acc[mi][1] = __builtin_amdgcn_mfma_f32_16x16x32_f16(a_, b1_, acc[mi][1], 0, 0, 0); \
    }                                                                               \
}

// W1: vmcnt for E==1 (9 when an o1 batch was issued in the E==0 window, else 1).
#define RBODY(O1CUR, O1NXT, I8, W1, LN)     \
    RSTEP(O1CUR, O1NXT, I8, 0, 1, LN)       \
    RSTEP(O1CUR, O1NXT, I8, 1, W1, LN)      \
    RSTEP(O1CUR, O1NXT, I8, 2, 1, LN)       \
    RSTEP(O1CUR, O1NXT, I8, 3, 1, LN)       \
    RSTEP(O1CUR, O1NXT, I8, 4, 1, LN)       \
    RSTEP(O1CUR, O1NXT, I8, 5, 1, LN)       \
    RSTEP(O1CUR, O1NXT, I8, 6, 1, LN)       \
    RSTEP(O1CUR, O1NXT, I8, 7, 1, LN)

template<int LAYER>
__global__ __launch_bounds__(256, 2)
void gemm_poly(const f16* __restrict__ Wswz, const f16* featg,
               const f16* ot1g, float* __restrict__ partials)
{
    __shared__ f16 wring[3][2048];           // 3 x 4KB ring

    constexpr int NLIN = (LAYER == 2) ? 4 : 8;   // global linear k-steps
    constexpr int CLIN = (LAYER == 2) ? 1 : 2;   // linear steps per split

    const int bid = blockIdx.x;
    const int rb = bid >> 4;                 // 0..31
    const int sp = (bid >> 2) & 3;           // k-split / j-window
    const int nb = bid & 3;                  // 64-col N quarter
    const int r0 = rb * 256;
    const int tid = threadIdx.x;
    const int wid = tid >> 6, lane = tid & 63;
    const int wr = wid >> 1, wc = wid & 1;   // 2M x 2N wave grid
    const int lhi = lane >> 4, llo = lane & 15;

    const f16* wsrc0 = Wswz + nb * 2048 + tid * 8;   // element units
    const f16* ot1_row  = ot1g  + (size_t)(r0 + wr * 128 + llo) * 128;  // + mi*2048
    const f16* feat_row = featg + (size_t)(r0 + wr * 128 + llo) * 128;

    f32x4 acc[8][2] = {};
    const int out_base = NLIN + sp * 128;

    // prologue: register-resident A slices + first o1 block
    f16x8 featreg[8], o1A[8], o1B[8];
#pragma unroll
    for (int mi = 0; mi < 8; ++mi) {
        featreg[mi] = *(const f16x8*)(feat_row + mi * 2048 + sp * 32 + lhi * 8);
        o1A[mi]     = *(const f16x8*)(ot1_row + mi * 2048);
    }

    // ---- linear steps (plain double-buffer, full drains; only CLIN of them) ----
    STAGE(CLIN * sp, 0);
    __syncthreads();
#pragma unroll
    for (int c = 0; c < CLIN; ++c) {
        if (c + 1 < CLIN) STAGE(CLIN * sp + c + 1, 1);
        const int s = CLIN * sp + c;
        const int col = s * 32 + lhi * 8;
        const f16* wb = &wring[c][0];
        const f16x8 b0 = *(const f16x8*)(wb + (wc * 128 + lane) * 8);
        const f16x8 b1 = *(const f16x8*)(wb + (wc * 128 + 64 + lane) * 8);
#pragma unroll
        for (int mi = 0; mi < 8; ++mi) {
            f16x8 a;
            if (LAYER == 2) a = *(const f16x8*)(ot1_row + mi * 2048 + col);
            else a = (col < 128) ? *(const f16x8*)(ot1_row + mi * 2048 + col)
                                 : *(const f16x8*)(feat_row + mi * 2048 + (col - 128));
            acc[mi][0] = __builtin_amdgcn_mfma_f32_16x16x32_f16(a, b0, acc[mi][0], 0, 0, 0);
            acc[mi][1] = __builtin_amdgcn_mfma_f32_16x16x32_f16(a, b1, acc[mi][1], 0, 0, 0);
        }
        __syncthreads();                     // drains vmcnt: next linear slot ready
    }

    // ---- ring prologue: stage outer steps 0,1 into slots 0,1 ----
    STAGE(out_base + 0, 0);
    STAGE(out_base + 1, 1);

    // ---- outer-product region: 128 ring steps ----
    for (int i8 = 0; i8 < 14; i8 += 2) {
        RBODY(o1A, o1B, i8,     9, 1)
        RBODY(o1B, o1A, i8 + 1, 9, 1)
    }
    RBODY(o1A, o1B, 14, 9, 1)
    RBODY(o1B, o1A, 15, 1, 0)

    // ---- epilogue: partial C (f32) ----
    float* pout = partials + (size_t)sp * PART_STRIDE
                + (size_t)(r0 + wr * 128) * 256 + nb * 64 + wc * 32 + llo;
#pragma unroll
    for (int mi = 0; mi < 8; ++mi)
#pragma unroll
        for (int ni = 0; ni < 2; ++ni)
#pragma unroll
            for (int q = 0; q < 4; ++q)
                pout[(size_t)(mi * 16 + lhi * 4 + q) * 256 + ni * 16] = acc[mi][ni][q];
}

#undef RBODY
#undef RSTEP
#undef WAITV
#undef WAITVX
#undef STAGE

// ---------------- K-split reduction + bias const + final-dot contribution ----------------
template<int LAYER>
__global__ __launch_bounds__(256)
void reduce_poly(const float* __restrict__ partials, const float* __restrict__ cvec,
                 const float* __restrict__ Wfc, f16* __restrict__ xf_out,
                 float* __restrict__ outacc, float* __restrict__ outp)
{
    const int r = blockIdx.x;
    const int n = threadIdx.x;
    const size_t idx = (size_t)r * 256 + n;
    float v = partials[idx] + partials[idx + PART_STRIDE]
            + partials[idx + 2 * PART_STRIDE] + partials[idx + 3 * PART_STRIDE];
    v += cvec[n];
    if (LAYER == 2 && n < 128)
        xf_out[(size_t)r * 128 + n] = (f16)v;       // row-major
    const int wseg = (LAYER == 2) ? (n < 128 ? 129 + n : 513 + (n - 128))
                                  : (n < 128 ? 257 + n : 641 + (n - 128));
    float p = v * Wfc[wseg];
#pragma unroll
    for (int off = 32; off; off >>= 1) p += __shfl_down(p, off);
    __shared__ float wp[4];
    if ((threadIdx.x & 63) == 0) wp[threadIdx.x >> 6] = p;
    __syncthreads();
    if (threadIdx.x == 0) {
        const float tot = wp[0] + wp[1] + wp[2] + wp[3];
        if (LAYER == 2) outacc[r] += tot;
        else            outp[r] = outacc[r] + tot;
    }
}

// ---------------- host launcher ----------------
extern "C" void kernel_launch(void* const* d_in, const int* in_sizes, int n_in,
                              void* d_out, int out_size, void* d_ws, size_t ws_size,
                              hipStream_t stream)
{
    (void)in_sizes; (void)n_in; (void)out_size; (void)ws_size;
    const float* x     = (const float*)d_in[0];
    const float* bias0 = (const float*)d_in[1];
    const float* Wf1   = (const float*)d_in[2];
    const float* bf1   = (const float*)d_in[3];
    const float* Wg1   = (const float*)d_in[4];
    const float* bg1   = (const float*)d_in[5];
    const float* Wf2   = (const float*)d_in[6];
    const float* bf2   = (const float*)d_in[7];
    const float* Wg2   = (const float*)d_in[8];
    const float* bg2   = (const float*)d_in[9];
    const float* Wf3   = (const float*)d_in[10];
    const float* bf3   = (const float*)d_in[11];
    const float* Wg3   = (const float*)d_in[12];
    const float* bg3   = (const float*)d_in[13];
    const float* Wfc   = (const float*)d_in[14];
    const float* bfc   = (const float*)d_in[15];
    float* out = (float*)d_out;

    char* ws = (char*)d_ws;
    f16*   W2s    = (f16*)(ws + OFF_W2);
    f16*   W3s    = (f16*)(ws + OFF_W3);
    f16*   ot1f16 = (f16*)(ws + OFF_OT1);
    f16*   xf2f16 = (f16*)(ws + OFF_XF2);
    float* c2     = (float*)(ws + OFF_C2);
    float* c3     = (float*)(ws + OFF_C3);
    float* outacc = (float*)(ws + OFF_ACC);
    float* parts  = (float*)(ws + OFF_PART);

    prep_fused<<<8241, 256, 0, stream>>>(x, bias0, Wf1, bf1, Wg1, bg1,
                                         Wf2, bf2, Wg2, bg2, Wf3, bf3, Wg3, bg3,
                                         Wfc, bfc, W2s, W3s, c2, c3, ot1f16, outacc);
    gemm_poly<2><<<512, 256, 0, stream>>>(W2s, ot1f16, ot1f16, parts);
    reduce_poly<2><<<8192, 256, 0, stream>>>(parts, c2, Wfc, xf2f16, outacc, out);
    gemm_poly<3><<<512, 256, 0, stream>>>(W3s, xf2f16, ot1f16, parts);
    reduce_poly<3><<<8192, 256, 0, stream>>>(parts, c3, Wfc, nullptr, outacc, out);
}

// Round 12
// 295.358 us; speedup vs baseline: 1.2464x; 1.0017x over previous
//
#include <hip/hip_runtime.h>

typedef _Float16 f16;
typedef _Float16 f16x8 __attribute__((ext_vector_type(8)));
typedef float f32x4 __attribute__((ext_vector_type(4)));

static constexpr size_t PART_STRIDE = (size_t)8192 * 256;

// ---------------- workspace layout (bytes) ----------------
static constexpr size_t OFF_W2   = 0;                                   // 516 steps * 8192 f16
static constexpr size_t SZ_W2    = (size_t)516 * 8192 * 2;
static constexpr size_t OFF_W3   = OFF_W2 + SZ_W2;                      // 520 steps * 8192 f16
static constexpr size_t SZ_W3    = (size_t)520 * 8192 * 2;
static constexpr size_t OFF_OT1  = OFF_W3 + SZ_W3;                      // 8192*128 f16 (row-major)
static constexpr size_t OFF_XF2  = OFF_OT1 + (size_t)8192 * 128 * 2;    // 8192*128 f16 (row-major)
static constexpr size_t OFF_C2   = OFF_XF2 + (size_t)8192 * 128 * 2;    // 256 f32
static constexpr size_t OFF_C3   = OFF_C2 + 1024;                       // 256 f32
static constexpr size_t OFF_ACC  = OFF_C3 + 1024;                       // 8192 f32
static constexpr size_t OFF_PART = OFF_ACC + 32768;                     // 4*8192*256 f32

// ---------------- fused prep: W2/W3 swizzle + bias consts + layer 1 ----------------
// K enumeration (jw outer, i inner); step s, lane l, elem e: kl=(l>>4)*8+e
//   L2: s<4  -> row = 1+s*32+kl ; else u=s-4: row = 129+(u&127)*128+(u>>7)*32+kl
//   L3: s<8  -> row = 1+s*32+kl ; else u=s-8: row = 257+(u&127)*128+(u>>7)*32+kl
// Wswz[((s*16+nt)*64+l)*8+e] = Weff[row][n=nt*16+(l&15)]; step stride 8192 f16.
template<int LAYER>
__device__ __forceinline__
void prep_w_body(int t, const float* __restrict__ Wf, const float* __restrict__ Wg,
                 f16* __restrict__ Wswz)
{
    const int s = t >> 10, rem = t & 1023;
    const int nt = rem >> 6, l = rem & 63;
    const int n = nt * 16 + (l & 15);
    const int klb = (l >> 4) * 8;
    f16x8 o;
#pragma unroll
    for (int e = 0; e < 8; ++e) {
        const int kl = klb + e;
        int row;
        if (LAYER == 2) {
            if (s < 4) row = 1 + s * 32 + kl;
            else { const int u = s - 4; row = 129 + (u & 127) * 128 + (u >> 7) * 32 + kl; }
        } else {
            if (s < 8) row = 1 + s * 32 + kl;
            else { const int u = s - 8; row = 257 + (u & 127) * 128 + (u >> 7) * 32 + kl; }
        }
        const float v = (n < 128) ? Wf[(size_t)row * 128 + n]
                                  : Wg[(size_t)row * 128 + (n - 128)];
        o[e] = (f16)v;
    }
    *(f16x8*)(Wswz + (size_t)t * 8) = o;
}

__global__ __launch_bounds__(256)
void prep_fused(const float* __restrict__ x, const float* __restrict__ bias0,
                const float* __restrict__ Wf1, const float* __restrict__ bf1,
                const float* __restrict__ Wg1, const float* __restrict__ bg1,
                const float* __restrict__ Wf2, const float* __restrict__ bf2,
                const float* __restrict__ Wg2, const float* __restrict__ bg2,
                const float* __restrict__ Wf3, const float* __restrict__ bf3,
                const float* __restrict__ Wg3, const float* __restrict__ bg3,
                const float* __restrict__ Wfc, const float* __restrict__ bfc,
                f16* __restrict__ W2s, f16* __restrict__ W3s,
                float* __restrict__ c2, float* __restrict__ c3,
                f16* __restrict__ ot1f16, float* __restrict__ outacc)
{
    const int bid = blockIdx.x;
    __shared__ float wp[4];
    if (bid < 2064) {
        prep_w_body<2>(bid * 256 + threadIdx.x, Wf2, Wg2, W2s);
    } else if (bid < 4144) {
        prep_w_body<3>((bid - 2064) * 256 + threadIdx.x, Wf3, Wg3, W3s);
    } else if (bid == 4144) {
        const int n = threadIdx.x;
        const float b0 = bias0[0];
        if (n < 128) { c2[n] = bf2[n] + b0 * Wf2[n]; c3[n] = bf3[n] + b0 * Wf3[n]; }
        else { const int m = n - 128; c2[n] = bg2[m] + b0 * Wg2[m]; c3[n] = bg3[m] + b0 * Wg3[m]; }
    } else {
        const int half = threadIdx.x >> 7;   // 2 rows per block
        const int n = threadIdx.x & 127;
        const int r = (bid - 4145) * 2 + half;
        const float b0 = bias0[0];
        float sf = b0 * Wf1[n] + bf1[n];
        float sg = b0 * Wg1[n] + bg1[n];
        const float* xr = x + (size_t)r * 64;
#pragma unroll 8
        for (int k = 0; k < 64; ++k) {
            const float xv = xr[k];
            sf = fmaf(xv, Wf1[(k + 1) * 128 + n], sf);
            sg = fmaf(xv, Wg1[(k + 1) * 128 + n], sg);
        }
        ot1f16[(size_t)r * 128 + n] = (f16)sf;     // row-major
        float p = sf * Wfc[1 + n] + sg * Wfc[385 + n];
#pragma unroll
        for (int off = 32; off; off >>= 1) p += __shfl_down(p, off);
        if ((threadIdx.x & 63) == 0) wp[threadIdx.x >> 6] = p;
        __syncthreads();
        if ((threadIdx.x & 127) == 0)
            outacc[r] = bfc[0] + b0 * Wfc[0] + wp[half * 2] + wp[half * 2 + 1];
    }
}

// ---------------- main GEMM v5b: 4-slot ring + B reg-double-buffer + setprio ----
// Block 256M x 64N, 4 waves (2M x 2N), wave tile 128M x 32N (mi=8, ni=2).
// Grid 32 rb x 4 sp x 4 nb = 512 -> 2 blocks/CU.
// Per step: vmcnt(counted) -> s_barrier -> ds_read B(t+1) into regs ->
// setprio(1) MFMA on B(t) regs setprio(0) -> STAGE(t+3) [-> o1 batch at E0].
// CROSS-WAVE RULE: any ds_read of a DMA'd slot must be preceded by
// (per-wave WAITV covering that slot's STAGE) THEN s_barrier — per-wave
// vmcnt says nothing about other waves' DMA chunks (R10 bug: prologue
// read of bP lacked the barrier).
// vmcnt ledger (per step issues: 1 STAGE, +8 o1-loads at E0/LN):
//   E1 with o1 batch at E0: vmcnt(9); otherwise vmcnt(1).

#define STAGE(S_W, BUF) do {                                                        \
    const f16* _src = wsrc0 + (size_t)(S_W) * 8192;                                 \
    __builtin_amdgcn_global_load_lds(                                               \
        (const __attribute__((address_space(1))) unsigned int*)_src,                \
        (__attribute__((address_space(3))) unsigned int*)&wring[BUF][tid * 8],      \
        16, 0, 0);                                                                  \
} while (0)

#define WAITVX(N) asm volatile("s_waitcnt vmcnt(" #N ") lgkmcnt(0)" ::: "memory")
#define WAITV(N) WAITVX(N)

// One ring step. BCUR: regs for this step (loaded last step); BNXT: filled here.
#define RSTEP(O1CUR, O1NXT, BCUR, BNXT, I8, E, WN, LN)                              \
{                                                                                   \
    const int s_ = (I8) * 8 + (E);                                                  \
    WAITV(WN);                                                                      \
    __builtin_amdgcn_s_barrier();                                                   \
    __builtin_amdgcn_sched_barrier(0);                                              \
    {   /* LDS->reg prefetch of NEXT step's B pair */                               \
        const f16* wb_ = &wring[(s_ + 1) & 3][0];                                   \
        BNXT[0] = *(const f16x8*)(wb_ + (wc * 128 + lane) * 8);                     \
        BNXT[1] = *(const f16x8*)(wb_ + (wc * 128 + 64 + lane) * 8);                \
    }                                                                               \
    __builtin_amdgcn_s_setprio(1);                                                  \
    _Pragma("unroll")                                                               \
    for (int mi = 0; mi < 8; ++mi) {                                                \
        const f16x8 a_ = featreg[mi] * O1CUR[mi][E];                                \
        acc[mi][0] = __builtin_amdgcn_mfma_f32_16x16x32_f16(a_, BCUR[0], acc[mi][0], 0, 0, 0); \
        acc[mi][1] = __builtin_amdgcn_mfma_f32_16x16x32_f16(a_, BCUR[1], acc[mi][1], 0, 0, 0); \
    }                                                                               \
    __builtin_amdgcn_s_setprio(0);                                                  \
    {   const int sn_ = (s_ + 3 < 128) ? s_ + 3 : 127;   /* dummy at tail */        \
        STAGE(out_base + sn_, (s_ + 3) & 3); }                                      \
    if ((LN) && (E) == 0) {                                                         \
        _Pragma("unroll")                                                           \
        for (int mi = 0; mi < 8; ++mi)                                              \
            O1NXT[mi] = *(const f16x8*)(ot1_row + mi * 2048 + ((I8) + 1) * 8);      \
    }                                                                               \
}

// W1: vmcnt at E==1 (9 iff an o1 batch was issued at E0, i.e. LN==1; else 1).
#define RBODY(O1CUR, O1NXT, I8, W1, LN)             \
    RSTEP(O1CUR, O1NXT, bP, bQ, I8, 0, 1, LN)       \
    RSTEP(O1CUR, O1NXT, bQ, bP, I8, 1, W1, LN)      \
    RSTEP(O1CUR, O1NXT, bP, bQ, I8, 2, 1, LN)       \
    RSTEP(O1CUR, O1NXT, bQ, bP, I8, 3, 1, LN)       \
    RSTEP(O1CUR, O1NXT, bP, bQ, I8, 4, 1, LN)       \
    RSTEP(O1CUR, O1NXT, bQ, bP, I8, 5, 1, LN)       \
    RSTEP(O1CUR, O1NXT, bP, bQ, I8, 6, 1, LN)       \
    RSTEP(O1CUR, O1NXT, bQ, bP, I8, 7, 1, LN)

template<int LAYER>
__global__ __launch_bounds__(256, 2)
void gemm_poly(const f16* __restrict__ Wswz, const f16* featg,
               const f16* ot1g, float* __restrict__ partials)
{
    __shared__ f16 wring[4][2048];           // 4 x 4KB ring

    constexpr int NLIN = (LAYER == 2) ? 4 : 8;   // global linear k-steps
    constexpr int CLIN = (LAYER == 2) ? 1 : 2;   // linear steps per split

    const int bid = blockIdx.x;
    const int rb = bid >> 4;                 // 0..31
    const int sp = (bid >> 2) & 3;           // k-split / j-window
    const int nb = bid & 3;                  // 64-col N quarter
    const int r0 = rb * 256;
    const int tid = threadIdx.x;
    const int wid = tid >> 6, lane = tid & 63;
    const int wr = wid >> 1, wc = wid & 1;   // 2M x 2N wave grid
    const int lhi = lane >> 4, llo = lane & 15;

    const f16* wsrc0 = Wswz + nb * 2048 + tid * 8;   // element units
    const f16* ot1_row  = ot1g  + (size_t)(r0 + wr * 128 + llo) * 128;  // + mi*2048
    const f16* feat_row = featg + (size_t)(r0 + wr * 128 + llo) * 128;

    f32x4 acc[8][2] = {};
    const int out_base = NLIN + sp * 128;

    // prologue: register-resident A slices + first o1 block
    f16x8 featreg[8], o1A[8], o1B[8];
#pragma unroll
    for (int mi = 0; mi < 8; ++mi) {
        featreg[mi] = *(const f16x8*)(feat_row + mi * 2048 + sp * 32 + lhi * 8);
        o1A[mi]     = *(const f16x8*)(ot1_row + mi * 2048);
    }

    // ---- linear steps (plain double-buffer in slots 0/1, full drains) ----
    STAGE(CLIN * sp, 0);
    __syncthreads();
#pragma unroll
    for (int c = 0; c < CLIN; ++c) {
        if (c + 1 < CLIN) STAGE(CLIN * sp + c + 1, 1);
        const int s = CLIN * sp + c;
        const int col = s * 32 + lhi * 8;
        const f16* wb = &wring[c][0];
        const f16x8 b0 = *(const f16x8*)(wb + (wc * 128 + lane) * 8);
        const f16x8 b1 = *(const f16x8*)(wb + (wc * 128 + 64 + lane) * 8);
#pragma unroll
        for (int mi = 0; mi < 8; ++mi) {
            f16x8 a;
            if (LAYER == 2) a = *(const f16x8*)(ot1_row + mi * 2048 + col);
            else a = (col < 128) ? *(const f16x8*)(ot1_row + mi * 2048 + col)
                                 : *(const f16x8*)(feat_row + mi * 2048 + (col - 128));
            acc[mi][0] = __builtin_amdgcn_mfma_f32_16x16x32_f16(a, b0, acc[mi][0], 0, 0, 0);
            acc[mi][1] = __builtin_amdgcn_mfma_f32_16x16x32_f16(a, b1, acc[mi][1], 0, 0, 0);
        }
        __syncthreads();                     // full drain: ring can be re-used
    }

    // ---- ring prologue: stage outer steps 0,1,2 into slots 0,1,2 ----
    STAGE(out_base + 0, 0);
    STAGE(out_base + 1, 1);
    STAGE(out_base + 2, 2);
    WAITV(2);                                // own STAGE(ob+0) chunk landed
    __builtin_amdgcn_s_barrier();            // ALL waves' slot-0 chunks landed (R10 fix)
    __builtin_amdgcn_sched_barrier(0);
    f16x8 bP[2], bQ[2];
    {
        const f16* wb = &wring[0][0];
        bP[0] = *(const f16x8*)(wb + (wc * 128 + lane) * 8);
        bP[1] = *(const f16x8*)(wb + (wc * 128 + 64 + lane) * 8);
    }

    // ---- outer-product region: 128 ring steps ----
    for (int i8 = 0; i8 < 14; i8 += 2) {
        RBODY(o1A, o1B, i8,     9, 1)
        RBODY(o1B, o1A, i8 + 1, 9, 1)
    }
    RBODY(o1A, o1B, 14, 9, 1)
    RBODY(o1B, o1A, 15, 1, 0)

    // ---- epilogue: partial C (f32) ----
    float* pout = partials + (size_t)sp * PART_STRIDE
                + (size_t)(r0 + wr * 128) * 256 + nb * 64 + wc * 32 + llo;
#pragma unroll
    for (int mi = 0; mi < 8; ++mi)
#pragma unroll
        for (int ni = 0; ni < 2; ++ni)
#pragma unroll
            for (int q = 0; q < 4; ++q)
                pout[(size_t)(mi * 16 + lhi * 4 + q) * 256 + ni * 16] = acc[mi][ni][q];
}

#undef RBODY
#undef RSTEP
#undef WAITV
#undef WAITVX
#undef STAGE

// ---------------- K-split reduction + bias const + final-dot contribution ----------------
template<int LAYER>
__global__ __launch_bounds__(256)
void reduce_poly(const float* __restrict__ partials, const float* __restrict__ cvec,
                 const float* __restrict__ Wfc, f16* __restrict__ xf_out,
                 float* __restrict__ outacc, float* __restrict__ outp)
{
    const int r = blockIdx.x;
    const int n = threadIdx.x;
    const size_t idx = (size_t)r * 256 + n;
    float v = partials[idx] + partials[idx + PART_STRIDE]
            + partials[idx + 2 * PART_STRIDE] + partials[idx + 3 * PART_STRIDE];
    v += cvec[n];
    if (LAYER == 2 && n < 128)
        xf_out[(size_t)r * 128 + n] = (f16)v;       // row-major
    const int wseg = (LAYER == 2) ? (n < 128 ? 129 + n : 513 + (n - 128))
                                  : (n < 128 ? 257 + n : 641 + (n - 128));
    float p = v * Wfc[wseg];
#pragma unroll
    for (int off = 32; off; off >>= 1) p += __shfl_down(p, off);
    __shared__ float wp[4];
    if ((threadIdx.x & 63) == 0) wp[threadIdx.x >> 6] = p;
    __syncthreads();
    if (threadIdx.x == 0) {
        const float tot = wp[0] + wp[1] + wp[2] + wp[3];
        if (LAYER == 2) outacc[r] += tot;
        else            outp[r] = outacc[r] + tot;
    }
}

// ---------------- host launcher ----------------
extern "C" void kernel_launch(void* const* d_in, const int* in_sizes, int n_in,
                              void* d_out, int out_size, void* d_ws, size_t ws_size,
                              hipStream_t stream)
{
    (void)in_sizes; (void)n_in; (void)out_size; (void)ws_size;
    const float* x     = (const float*)d_in[0];
    const float* bias0 = (const float*)d_in[1];
    const float* Wf1   = (const float*)d_in[2];
    const float* bf1   = (const float*)d_in[3];
    const float* Wg1   = (const float*)d_in[4];
    const float* bg1   = (const float*)d_in[5];
    const float* Wf2   = (const float*)d_in[6];
    const float* bf2   = (const float*)d_in[7];
    const float* Wg2   = (const float*)d_in[8];
    const float* bg2   = (const float*)d_in[9];
    const float* Wf3   = (const float*)d_in[10];
    const float* bf3   = (const float*)d_in[11];
    const float* Wg3   = (const float*)d_in[12];
    const float* bg3   = (const float*)d_in[13];
    const float* Wfc   = (const float*)d_in[14];
    const float* bfc   = (const float*)d_in[15];
    float* out = (float*)d_out;

    char* ws = (char*)d_ws;
    f16*   W2s    = (f16*)(ws + OFF_W2);
    f16*   W3s    = (f16*)(ws + OFF_W3);
    f16*   ot1f16 = (f16*)(ws + OFF_OT1);
    f16*   xf2f16 = (f16*)(ws + OFF_XF2);
    float* c2     = (float*)(ws + OFF_C2);
    float* c3     = (float*)(ws + OFF_C3);
    float* outacc = (float*)(ws + OFF_ACC);
    float* parts  = (float*)(ws + OFF_PART);

    prep_fused<<<8241, 256, 0, stream>>>(x, bias0, Wf1, bf1, Wg1, bg1,
                                         Wf2, bf2, Wg2, bg2, Wf3, bf3, Wg3, bg3,
                                         Wfc, bfc, W2s, W3s, c2, c3, ot1f16, outacc);
    gemm_poly<2><<<512, 256, 0, stream>>>(W2s, ot1f16, ot1f16, parts);
    reduce_poly<2><<<8192, 256, 0, stream>>>(parts, c2, Wfc, xf2f16, outacc, out);
    gemm_poly<3><<<512, 256, 0, stream>>>(W3s, xf2f16, ot1f16, parts);
    reduce_poly<3><<<8192, 256, 0, stream>>>(parts, c3, Wfc, nullptr, outacc, out);
}